// Round 5
// baseline (144.251 us; speedup 1.0000x reference)
//
#include <hip/hip_runtime.h>
#include <math.h>

#define HID 64

typedef __attribute__((ext_vector_type(8))) short short8;
typedef __attribute__((ext_vector_type(4))) float f32x4;

union FragU {
    uint4 q;
    short8 v;
    uint32_t u[4];
};

__device__ __forceinline__ uint32_t cvt_pk_bf16(float lo, float hi) {
    uint32_t r;
    asm("v_cvt_pk_bf16_f32 %0, %1, %2" : "=v"(r) : "v"(lo), "v"(hi));
    return r;
}

// ---------------------------------------------------------------------------
// Edge MLP (K1): msg[e] = MLP3([nf[src], nf[dst], ef])  (coalesced store,
// NO atomics when mode==0). mode==1 is the fused fallback (atomicAdd into
// out[dst[e]]) used only if ws_size can't hold the msg buffer.
// Internals identical to round-4 kernel to isolate the split's effect.
// ---------------------------------------------------------------------------
__global__ __launch_bounds__(256) void edge_mlp_kernel(
    const float* __restrict__ nf, const float* __restrict__ ef,
    const int* __restrict__ src, const int* __restrict__ dst,
    const float* __restrict__ w1, const float* __restrict__ b1,
    const float* __restrict__ w2, const float* __restrict__ b2,
    const float* __restrict__ w3, const float* __restrict__ b3,
    float* __restrict__ outp, int E, int mode)
{
    __shared__ uint4 hbuf[256 * 8];

    const int tid  = threadIdx.x;
    const int lane = tid & 63;
    const int wid  = tid >> 6;
    const int g    = lane >> 4;
    const int eL   = lane & 15;

    // A-fragments = W2^T
    FragU af[4][2];
#pragma unroll
    for (int t = 0; t < 4; ++t)
#pragma unroll
        for (int h = 0; h < 2; ++h)
#pragma unroll
            for (int e2 = 0; e2 < 4; ++e2) {
                int k0 = h * 32 + g * 8 + 2 * e2;
                float v0 = w2[(k0    ) * HID + t * 16 + eL];
                float v1 = w2[(k0 + 1) * HID + t * 16 + eL];
                af[t][h].u[e2] = cvt_pk_bf16(v0, v1);
            }

    float b2v[16], w3v[16];
#pragma unroll
    for (int t = 0; t < 4; ++t)
#pragma unroll
        for (int r = 0; r < 4; ++r) {
            int j = t * 16 + g * 4 + r;
            b2v[t * 4 + r] = b2[j];
            w3v[t * 4 + r] = w3[j];
        }
    const float b3c = b3[0];

    const int e0 = blockIdx.x * 256;
    {
        int eidx = e0 + tid;
        int ei = eidx < E ? eidx : E - 1;
        float a = nf[src[ei]];
        float b = nf[dst[ei]];
        float c = ef[ei];

        uint32_t pk[32];
#pragma unroll
        for (int k2 = 0; k2 < 32; ++k2) {
            int k0 = 2 * k2, k1 = 2 * k2 + 1;
            float h0 = fmaxf(fmaf(a, w1[k0], fmaf(b, w1[HID + k0], fmaf(c, w1[2 * HID + k0], b1[k0]))), 0.f);
            float h1 = fmaxf(fmaf(a, w1[k1], fmaf(b, w1[HID + k1], fmaf(c, w1[2 * HID + k1], b1[k1]))), 0.f);
            pk[k2] = cvt_pk_bf16(h0, h1);
        }

        uint4* rowp = &hbuf[tid * 8];
        int sw = tid & 7;
#pragma unroll
        for (int ch = 0; ch < 8; ++ch)
            rowp[ch ^ sw] = make_uint4(pk[4 * ch], pk[4 * ch + 1], pk[4 * ch + 2], pk[4 * ch + 3]);
    }

#pragma unroll
    for (int s = 0; s < 4; ++s) {
        int row = wid * 64 + s * 16 + eL;
        int sw  = lane & 7;
        FragU bf0, bf1;
        bf0.q = hbuf[row * 8 + ((    g) ^ sw)];
        bf1.q = hbuf[row * 8 + ((4 + g) ^ sw)];

        f32x4 ac[4];
#pragma unroll
        for (int t = 0; t < 4; ++t) {
            ac[t][0] = b2v[t * 4 + 0];
            ac[t][1] = b2v[t * 4 + 1];
            ac[t][2] = b2v[t * 4 + 2];
            ac[t][3] = b2v[t * 4 + 3];
            ac[t] = __builtin_amdgcn_mfma_f32_16x16x32_bf16(af[t][0].v, bf0.v, ac[t], 0, 0, 0);
            ac[t] = __builtin_amdgcn_mfma_f32_16x16x32_bf16(af[t][1].v, bf1.v, ac[t], 0, 0, 0);
        }

        float p = 0.f;
#pragma unroll
        for (int t = 0; t < 4; ++t)
#pragma unroll
            for (int r = 0; r < 4; ++r)
                p = fmaf(fmaxf(ac[t][r], 0.f), w3v[t * 4 + r], p);

        p += __shfl_xor(p, 16);
        p += __shfl_xor(p, 32);

        if (lane < 16) {
            int ge = e0 + wid * 64 + s * 16 + lane;
            if (ge < E) {
                if (mode == 0)
                    outp[ge] = p + b3c;
                else
                    atomicAdd(&outp[dst[ge]], p + b3c);
            }
        }
    }
}

// ---------------------------------------------------------------------------
// Scatter stage (K2): aggR[(e & rmask)*N + dst[e]] += msg[e]
// 4 edges/thread, dwordx4 loads, fire-and-forget atomics. Replication by
// low edge bits cuts same-address collisions (avg 32 -> 32/R).
// ---------------------------------------------------------------------------
__global__ __launch_bounds__(256) void scatter_kernel(
    const float* __restrict__ msg, const int* __restrict__ dst,
    float* __restrict__ aggR, int E, int N, int rmask)
{
    int t = blockIdx.x * blockDim.x + threadIdx.x;
    int e = t * 4;
    if (e + 3 < E) {
        float4 m = *reinterpret_cast<const float4*>(msg + e);
        int4   d = *reinterpret_cast<const int4*>(dst + e);
        atomicAdd(&aggR[(size_t)((e    ) & rmask) * N + d.x], m.x);
        atomicAdd(&aggR[(size_t)((e + 1) & rmask) * N + d.y], m.y);
        atomicAdd(&aggR[(size_t)((e + 2) & rmask) * N + d.z], m.z);
        atomicAdd(&aggR[(size_t)((e + 3) & rmask) * N + d.w], m.w);
    } else {
        for (int k = e; k < E; ++k)
            atomicAdd(&aggR[(size_t)(k & rmask) * N + dst[k]], msg[k]);
    }
}

// ---------------------------------------------------------------------------
// Node stage (MFMA): 1 wave per block, 64 nodes. x1 = sum over R replicas.
// Segmented shfl_up scan over sorted gid, one atomic per run tail.
// ---------------------------------------------------------------------------
__global__ __launch_bounds__(64) void node_mfma_kernel(
    const float* __restrict__ nf, const float* __restrict__ agg,
    const int* __restrict__ gid,
    const float* __restrict__ nw1, const float* __restrict__ nb1,
    const float* __restrict__ nw2, const float* __restrict__ nb2,
    const float* __restrict__ nw3, const float* __restrict__ nb3,
    const float* __restrict__ mw1, const float* __restrict__ mb1,
    const float* __restrict__ mw2, const float* __restrict__ mb2,
    const float* __restrict__ mw3, const float* __restrict__ mb3,
    float* __restrict__ rd, int N, int R)
{
    __shared__ uint4 hbuf[64 * 8];
    __shared__ float unfbuf[64];
    __shared__ float obuf[64];

    const int lane = threadIdx.x;
    const int g    = lane >> 4;
    const int eL   = lane & 15;
    const int sw   = lane & 7;

    const int base = blockIdx.x * 64;
    const int idx  = base + lane;
    const int i    = idx < N ? idx : N - 1;
    const float x0 = nf[i];
    float x1 = 0.f;
    for (int r = 0; r < R; ++r)
        x1 += agg[(size_t)r * N + i];

    // ================= MLP-N: [nf, agg] -> unf =================
    {
        uint32_t pk[32];
#pragma unroll
        for (int k2 = 0; k2 < 32; ++k2) {
            int k0 = 2 * k2, k1 = 2 * k2 + 1;
            float h0 = fmaxf(fmaf(x0, nw1[k0], fmaf(x1, nw1[HID + k0], nb1[k0])), 0.f);
            float h1 = fmaxf(fmaf(x0, nw1[k1], fmaf(x1, nw1[HID + k1], nb1[k1])), 0.f);
            pk[k2] = cvt_pk_bf16(h0, h1);
        }
        uint4* rowp = &hbuf[lane * 8];
#pragma unroll
        for (int ch = 0; ch < 8; ++ch)
            rowp[ch ^ sw] = make_uint4(pk[4 * ch], pk[4 * ch + 1], pk[4 * ch + 2], pk[4 * ch + 3]);

        FragU af[4][2];
#pragma unroll
        for (int t = 0; t < 4; ++t)
#pragma unroll
            for (int h = 0; h < 2; ++h)
#pragma unroll
                for (int e2 = 0; e2 < 4; ++e2) {
                    int k0 = h * 32 + g * 8 + 2 * e2;
                    float v0 = nw2[(k0    ) * HID + t * 16 + eL];
                    float v1 = nw2[(k0 + 1) * HID + t * 16 + eL];
                    af[t][h].u[e2] = cvt_pk_bf16(v0, v1);
                }
        float b2v[16], w3v[16];
#pragma unroll
        for (int t = 0; t < 4; ++t)
#pragma unroll
            for (int r = 0; r < 4; ++r) {
                int j = t * 16 + g * 4 + r;
                b2v[t * 4 + r] = nb2[j];
                w3v[t * 4 + r] = nw3[j];
            }
        const float b3c = nb3[0];

#pragma unroll
        for (int s = 0; s < 4; ++s) {
            int row = s * 16 + eL;
            FragU bf0, bf1;
            bf0.q = hbuf[row * 8 + ((    g) ^ (row & 7))];
            bf1.q = hbuf[row * 8 + ((4 + g) ^ (row & 7))];

            f32x4 ac[4];
#pragma unroll
            for (int t = 0; t < 4; ++t) {
                ac[t][0] = b2v[t * 4 + 0];
                ac[t][1] = b2v[t * 4 + 1];
                ac[t][2] = b2v[t * 4 + 2];
                ac[t][3] = b2v[t * 4 + 3];
                ac[t] = __builtin_amdgcn_mfma_f32_16x16x32_bf16(af[t][0].v, bf0.v, ac[t], 0, 0, 0);
                ac[t] = __builtin_amdgcn_mfma_f32_16x16x32_bf16(af[t][1].v, bf1.v, ac[t], 0, 0, 0);
            }

            float p = 0.f;
#pragma unroll
            for (int t = 0; t < 4; ++t)
#pragma unroll
                for (int r = 0; r < 4; ++r)
                    p = fmaf(fmaxf(ac[t][r], 0.f), w3v[t * 4 + r], p);

            p += __shfl_xor(p, 16);
            p += __shfl_xor(p, 32);

            if (lane < 16)
                unfbuf[s * 16 + lane] = p + b3c;
        }
    }

    const float unf = unfbuf[lane];

    // ================= MLP-M: unf -> sigmoid(out) =================
    {
        uint32_t pk[32];
#pragma unroll
        for (int k2 = 0; k2 < 32; ++k2) {
            int k0 = 2 * k2, k1 = 2 * k2 + 1;
            float h0 = fmaxf(fmaf(unf, mw1[k0], mb1[k0]), 0.f);
            float h1 = fmaxf(fmaf(unf, mw1[k1], mb1[k1]), 0.f);
            pk[k2] = cvt_pk_bf16(h0, h1);
        }
        uint4* rowp = &hbuf[lane * 8];
#pragma unroll
        for (int ch = 0; ch < 8; ++ch)
            rowp[ch ^ sw] = make_uint4(pk[4 * ch], pk[4 * ch + 1], pk[4 * ch + 2], pk[4 * ch + 3]);

        FragU af[4][2];
#pragma unroll
        for (int t = 0; t < 4; ++t)
#pragma unroll
            for (int h = 0; h < 2; ++h)
#pragma unroll
                for (int e2 = 0; e2 < 4; ++e2) {
                    int k0 = h * 32 + g * 8 + 2 * e2;
                    float v0 = mw2[(k0    ) * HID + t * 16 + eL];
                    float v1 = mw2[(k0 + 1) * HID + t * 16 + eL];
                    af[t][h].u[e2] = cvt_pk_bf16(v0, v1);
                }
        float b2v[16], w3v[16];
#pragma unroll
        for (int t = 0; t < 4; ++t)
#pragma unroll
            for (int r = 0; r < 4; ++r) {
                int j = t * 16 + g * 4 + r;
                b2v[t * 4 + r] = mb2[j];
                w3v[t * 4 + r] = mw3[j];
            }
        const float b3c = mb3[0];

#pragma unroll
        for (int s = 0; s < 4; ++s) {
            int row = s * 16 + eL;
            FragU bf0, bf1;
            bf0.q = hbuf[row * 8 + ((    g) ^ (row & 7))];
            bf1.q = hbuf[row * 8 + ((4 + g) ^ (row & 7))];

            f32x4 ac[4];
#pragma unroll
            for (int t = 0; t < 4; ++t) {
                ac[t][0] = b2v[t * 4 + 0];
                ac[t][1] = b2v[t * 4 + 1];
                ac[t][2] = b2v[t * 4 + 2];
                ac[t][3] = b2v[t * 4 + 3];
                ac[t] = __builtin_amdgcn_mfma_f32_16x16x32_bf16(af[t][0].v, bf0.v, ac[t], 0, 0, 0);
                ac[t] = __builtin_amdgcn_mfma_f32_16x16x32_bf16(af[t][1].v, bf1.v, ac[t], 0, 0, 0);
            }

            float p = 0.f;
#pragma unroll
            for (int t = 0; t < 4; ++t)
#pragma unroll
                for (int r = 0; r < 4; ++r)
                    p = fmaf(fmaxf(ac[t][r], 0.f), w3v[t * 4 + r], p);

            p += __shfl_xor(p, 16);
            p += __shfl_xor(p, 32);

            if (lane < 16) {
                float o = p + b3c;
                obuf[s * 16 + lane] = 1.0f / (1.0f + expf(-o));
            }
        }
    }

    // ---- segmented reduction over sorted gid, one atomic per run tail ----
    {
        const bool ok = idx < N;
        float v = ok ? obuf[lane] : 0.0f;
        int   gg = gid[i];

#pragma unroll
        for (int d = 1; d < 64; d <<= 1) {
            float vup = __shfl_up(v, d);
            int   gup = __shfl_up(gg, d);
            if (lane >= d && gup == gg) v += vup;
        }
        int gdn = __shfl_down(gg, 1);
        bool tail = (lane == 63) || (gdn != gg);
        if (tail)
            atomicAdd(&rd[gg], v);
    }
}

__global__ void readout_kernel(const float* __restrict__ rd,
                               float* __restrict__ out, int G)
{
    int g = blockIdx.x * blockDim.x + threadIdx.x;
    if (g < G) out[g] = 1.0f / (1.0f + expf(-rd[g]));
}

extern "C" void kernel_launch(void* const* d_in, const int* in_sizes, int n_in,
                              void* d_out, int out_size, void* d_ws, size_t ws_size,
                              hipStream_t stream)
{
    const float* nf  = (const float*)d_in[0];
    const float* ef  = (const float*)d_in[1];
    const int*   src = (const int*)  d_in[2];
    const int*   dst = (const int*)  d_in[3];
    const int*   gid = (const int*)  d_in[4];

    const float* e_w1 = (const float*)d_in[5];
    const float* e_b1 = (const float*)d_in[6];
    const float* e_w2 = (const float*)d_in[7];
    const float* e_b2 = (const float*)d_in[8];
    const float* e_w3 = (const float*)d_in[9];
    const float* e_b3 = (const float*)d_in[10];

    const float* n_w1 = (const float*)d_in[11];
    const float* n_b1 = (const float*)d_in[12];
    const float* n_w2 = (const float*)d_in[13];
    const float* n_b2 = (const float*)d_in[14];
    const float* n_w3 = (const float*)d_in[15];
    const float* n_b3 = (const float*)d_in[16];

    const float* m_w1 = (const float*)d_in[17];
    const float* m_b1 = (const float*)d_in[18];
    const float* m_w2 = (const float*)d_in[19];
    const float* m_b2 = (const float*)d_in[20];
    const float* m_w3 = (const float*)d_in[21];
    const float* m_b3 = (const float*)d_in[22];

    const int N = in_sizes[0];   // 50000 nodes
    const int E = in_sizes[2];   // 1600000 edges
    const int G = out_size;      // 512 graphs

    // Choose replica count R (power of 2, <=8) such that
    // [aggR: R*N][rd: G][msg: E] floats fit in ws.
    int R = 8;
    while (R > 1 && ((size_t)R * N + G + E) * sizeof(float) > ws_size) R >>= 1;
    bool split = ((size_t)R * N + G + E) * sizeof(float) <= ws_size;

    float* aggR = (float*)d_ws;                 // R*N floats
    float* rd   = aggR + (size_t)R * N;         // G floats
    float* msg  = rd + G;                       // E floats
    float* out  = (float*)d_out;

    hipMemsetAsync(d_ws, 0, ((size_t)R * N + G) * sizeof(float), stream);

    if (split) {
        edge_mlp_kernel<<<(E + 255) / 256, 256, 0, stream>>>(
            nf, ef, src, dst, e_w1, e_b1, e_w2, e_b2, e_w3, e_b3, msg, E, 0);
        scatter_kernel<<<(E / 4 + 255) / 256, 256, 0, stream>>>(
            msg, dst, aggR, E, N, R - 1);
    } else {
        R = 1;
        edge_mlp_kernel<<<(E + 255) / 256, 256, 0, stream>>>(
            nf, ef, src, dst, e_w1, e_b1, e_w2, e_b2, e_w3, e_b3, aggR, E, 1);
    }

    node_mfma_kernel<<<(N + 63) / 64, 64, 0, stream>>>(
        nf, aggR, gid,
        n_w1, n_b1, n_w2, n_b2, n_w3, n_b3,
        m_w1, m_b1, m_w2, m_b2, m_w3, m_b3,
        rd, N, R);

    readout_kernel<<<(G + 255) / 256, 256, 0, stream>>>(rd, out, G);
}

// Round 6
// 85.851 us; speedup vs baseline: 1.6803x; 1.6803x over previous
//
#include <hip/hip_runtime.h>
#include <math.h>

#define HID 64
#define BKT_SHIFT 13                 // 8192 nodes per bucket
#define BKT_RANGE 8192
#define CCHUNK 32                    // wave-chunks per bucket in phase B

typedef __attribute__((ext_vector_type(8))) short short8;
typedef __attribute__((ext_vector_type(4))) float f32x4;
typedef unsigned long long ull;

union FragU {
    uint4 q;
    short8 v;
    uint32_t u[4];
};

__device__ __forceinline__ uint32_t cvt_pk_bf16(float lo, float hi) {
    uint32_t r;
    asm("v_cvt_pk_bf16_f32 %0, %1, %2" : "=v"(r) : "v"(lo), "v"(hi));
    return r;
}

// ---------------------------------------------------------------------------
// Edge MLP + bucket append: msg = MLP3([nf[src], nf[dst], ef]).
// mode 0: group the wave's 64 msgs by bucket (dst>>13), write records
//         coalesced into the wave-private region recs[wave*64 .. +64) and
//         one packed u64 of per-bucket offsets. ZERO atomics.
// mode 1: fallback — atomicAdd into agg[dst[e]] (round-4 path).
// ---------------------------------------------------------------------------
__global__ __launch_bounds__(256) void edge_mlp_kernel(
    const float* __restrict__ nf, const float* __restrict__ ef,
    const int* __restrict__ src, const int* __restrict__ dst,
    const float* __restrict__ w1, const float* __restrict__ b1,
    const float* __restrict__ w2, const float* __restrict__ b2,
    const float* __restrict__ w3, const float* __restrict__ b3,
    uint2* __restrict__ recs, ull* __restrict__ offs,
    float* __restrict__ aggFb, int E, int B, int mode)
{
    __shared__ uint4 hbuf[256 * 8];

    const int tid  = threadIdx.x;
    const int lane = tid & 63;
    const int wid  = tid >> 6;
    const int g    = lane >> 4;
    const int eL   = lane & 15;

    // A-fragments = W2^T
    FragU af[4][2];
#pragma unroll
    for (int t = 0; t < 4; ++t)
#pragma unroll
        for (int h = 0; h < 2; ++h)
#pragma unroll
            for (int e2 = 0; e2 < 4; ++e2) {
                int k0 = h * 32 + g * 8 + 2 * e2;
                float v0 = w2[(k0    ) * HID + t * 16 + eL];
                float v1 = w2[(k0 + 1) * HID + t * 16 + eL];
                af[t][h].u[e2] = cvt_pk_bf16(v0, v1);
            }

    float b2v[16], w3v[16];
#pragma unroll
    for (int t = 0; t < 4; ++t)
#pragma unroll
        for (int r = 0; r < 4; ++r) {
            int j = t * 16 + g * 4 + r;
            b2v[t * 4 + r] = b2[j];
            w3v[t * 4 + r] = w3[j];
        }
    const float b3c = b3[0];

    const int e0 = blockIdx.x * 256;
    const int eidx = e0 + tid;
    const int ei = eidx < E ? eidx : E - 1;
    const int dmine = dst[ei];
    {
        float a = nf[src[ei]];
        float b = nf[dmine];
        float c = ef[ei];

        uint32_t pk[32];
#pragma unroll
        for (int k2 = 0; k2 < 32; ++k2) {
            int k0 = 2 * k2, k1 = 2 * k2 + 1;
            float h0 = fmaxf(fmaf(a, w1[k0], fmaf(b, w1[HID + k0], fmaf(c, w1[2 * HID + k0], b1[k0]))), 0.f);
            float h1 = fmaxf(fmaf(a, w1[k1], fmaf(b, w1[HID + k1], fmaf(c, w1[2 * HID + k1], b1[k1]))), 0.f);
            pk[k2] = cvt_pk_bf16(h0, h1);
        }

        uint4* rowp = &hbuf[tid * 8];
        int sw = tid & 7;
#pragma unroll
        for (int ch = 0; ch < 8; ++ch)
            rowp[ch ^ sw] = make_uint4(pk[4 * ch], pk[4 * ch + 1], pk[4 * ch + 2], pk[4 * ch + 3]);
    }

    float mymsg = 0.f;   // msg for edge e0 + wid*64 + lane

#pragma unroll
    for (int s = 0; s < 4; ++s) {
        int row = wid * 64 + s * 16 + eL;
        int sw  = lane & 7;
        FragU bf0, bf1;
        bf0.q = hbuf[row * 8 + ((    g) ^ sw)];
        bf1.q = hbuf[row * 8 + ((4 + g) ^ sw)];

        f32x4 ac[4];
#pragma unroll
        for (int t = 0; t < 4; ++t) {
            ac[t][0] = b2v[t * 4 + 0];
            ac[t][1] = b2v[t * 4 + 1];
            ac[t][2] = b2v[t * 4 + 2];
            ac[t][3] = b2v[t * 4 + 3];
            ac[t] = __builtin_amdgcn_mfma_f32_16x16x32_bf16(af[t][0].v, bf0.v, ac[t], 0, 0, 0);
            ac[t] = __builtin_amdgcn_mfma_f32_16x16x32_bf16(af[t][1].v, bf1.v, ac[t], 0, 0, 0);
        }

        float p = 0.f;
#pragma unroll
        for (int t = 0; t < 4; ++t)
#pragma unroll
            for (int r = 0; r < 4; ++r)
                p = fmaf(fmaxf(ac[t][r], 0.f), w3v[t * 4 + r], p);

        p += __shfl_xor(p, 16);
        p += __shfl_xor(p, 32);       // all 64 lanes: msg of edge s*16 + (lane&15)

        if (s == (lane >> 4)) mymsg = p + b3c;
    }

    const bool valid = eidx < E;

    if (mode == 1) {
        if (valid) atomicAdd(&aggFb[dmine], mymsg);
        return;
    }

    // ---- bucket append: group 64 edges by bucket, coalesced wave-private write ----
    const int bkt = dmine >> BKT_SHIFT;
    const ull lt = (1ull << lane) - 1;
    int myslot = 0;
    int off = 0;
    uint32_t pack_lo = 0, pack_hi = 0;
    for (int b = 0; b < B; ++b) {
        if (b < 4) pack_lo |= (uint32_t)off << (8 * b);
        else       pack_hi |= (uint32_t)off << (8 * (b - 4));
        ull m = __ballot(valid && bkt == b);
        if (valid && bkt == b) myslot = off + (int)__popcll(m & lt);
        off += (int)__popcll(m);
    }
    pack_hi |= (uint32_t)off << 24;   // total in byte 7

    const size_t wgl = (size_t)blockIdx.x * 4 + wid;
    if (valid) recs[wgl * 64 + myslot] = make_uint2((uint32_t)dmine, __float_as_uint(mymsg));
    if (lane == 0) offs[wgl] = ((ull)pack_hi << 32) | (ull)pack_lo;
}

// ---------------------------------------------------------------------------
// Phase B: block (b,c) accumulates bucket b's records from wave-chunk c into
// a 32KB LDS array (LDS atomics), then writes a dense partial plane.
// ---------------------------------------------------------------------------
__global__ __launch_bounds__(256) void bucket_accum_kernel(
    const uint2* __restrict__ recs, const ull* __restrict__ offs,
    float* __restrict__ partial, int NW, int B)
{
    __shared__ float acc[BKT_RANGE];

    const int b = blockIdx.x / CCHUNK;
    const int c = blockIdx.x % CCHUNK;

    for (int i = threadIdx.x; i < BKT_RANGE; i += 256) acc[i] = 0.f;
    __syncthreads();

    const int wpc = (NW + CCHUNK - 1) / CCHUNK;
    const int w0 = c * wpc;
    const int w1 = (w0 + wpc < NW) ? w0 + wpc : NW;
    const int nb = b + 1;
    const int base_node = b << BKT_SHIFT;

    for (int w = w0 + threadIdx.x; w < w1; w += 256) {
        ull ov = offs[w];
        uint32_t lo = (uint32_t)ov, hi = (uint32_t)(ov >> 32);
        int ob = (int)(((b  < 4) ? (lo >> (8 * b))        : (hi >> (8 * (b  - 4)))) & 0xFF);
        int oe = (int)(((nb < 4) ? (lo >> (8 * nb))       : (hi >> (8 * (nb - 4)))) & 0xFF);
        const uint2* rb = recs + (size_t)w * 64;
        for (int r = ob; r < oe; ++r) {
            uint2 rec = rb[r];
            atomicAdd(&acc[(int)rec.x - base_node], __uint_as_float(rec.y));
        }
    }
    __syncthreads();

    float* pb = partial + ((size_t)b * CCHUNK + c) * BKT_RANGE;
    for (int i = threadIdx.x; i < BKT_RANGE; i += 256) pb[i] = acc[i];
}

// ---------------------------------------------------------------------------
// Phase C: agg[n] = sum over chunks of partial[bucket(n)][c][n_local]
// (coalesced: consecutive threads read consecutive addresses per plane)
// ---------------------------------------------------------------------------
__global__ __launch_bounds__(256) void bucket_reduce_kernel(
    const float* __restrict__ partial, float* __restrict__ agg, int N)
{
    int n = blockIdx.x * 256 + threadIdx.x;
    if (n >= N) return;
    int b = n >> BKT_SHIFT, nl = n & (BKT_RANGE - 1);
    const float* p = partial + (size_t)b * CCHUNK * BKT_RANGE + nl;
    float s = 0.f;
#pragma unroll 8
    for (int c = 0; c < CCHUNK; ++c) s += p[(size_t)c * BKT_RANGE];
    agg[n] = s;
}

// ---------------------------------------------------------------------------
// Node stage (MFMA): 1 wave per block, 64 nodes; both MLPs via MFMA;
// segmented shfl_up scan over sorted gid, one atomic per run tail.
// ---------------------------------------------------------------------------
__global__ __launch_bounds__(64) void node_mfma_kernel(
    const float* __restrict__ nf, const float* __restrict__ agg,
    const int* __restrict__ gid,
    const float* __restrict__ nw1, const float* __restrict__ nb1,
    const float* __restrict__ nw2, const float* __restrict__ nb2,
    const float* __restrict__ nw3, const float* __restrict__ nb3,
    const float* __restrict__ mw1, const float* __restrict__ mb1,
    const float* __restrict__ mw2, const float* __restrict__ mb2,
    const float* __restrict__ mw3, const float* __restrict__ mb3,
    float* __restrict__ rd, int N)
{
    __shared__ uint4 hbuf[64 * 8];
    __shared__ float unfbuf[64];
    __shared__ float obuf[64];

    const int lane = threadIdx.x;
    const int g    = lane >> 4;
    const int eL   = lane & 15;
    const int sw   = lane & 7;

    const int base = blockIdx.x * 64;
    const int idx  = base + lane;
    const int i    = idx < N ? idx : N - 1;
    const float x0 = nf[i];
    const float x1 = agg[i];

    // ================= MLP-N: [nf, agg] -> unf =================
    {
        uint32_t pk[32];
#pragma unroll
        for (int k2 = 0; k2 < 32; ++k2) {
            int k0 = 2 * k2, k1 = 2 * k2 + 1;
            float h0 = fmaxf(fmaf(x0, nw1[k0], fmaf(x1, nw1[HID + k0], nb1[k0])), 0.f);
            float h1 = fmaxf(fmaf(x0, nw1[k1], fmaf(x1, nw1[HID + k1], nb1[k1])), 0.f);
            pk[k2] = cvt_pk_bf16(h0, h1);
        }
        uint4* rowp = &hbuf[lane * 8];
#pragma unroll
        for (int ch = 0; ch < 8; ++ch)
            rowp[ch ^ sw] = make_uint4(pk[4 * ch], pk[4 * ch + 1], pk[4 * ch + 2], pk[4 * ch + 3]);

        FragU af[4][2];
#pragma unroll
        for (int t = 0; t < 4; ++t)
#pragma unroll
            for (int h = 0; h < 2; ++h)
#pragma unroll
                for (int e2 = 0; e2 < 4; ++e2) {
                    int k0 = h * 32 + g * 8 + 2 * e2;
                    float v0 = nw2[(k0    ) * HID + t * 16 + eL];
                    float v1 = nw2[(k0 + 1) * HID + t * 16 + eL];
                    af[t][h].u[e2] = cvt_pk_bf16(v0, v1);
                }
        float b2v[16], w3v[16];
#pragma unroll
        for (int t = 0; t < 4; ++t)
#pragma unroll
            for (int r = 0; r < 4; ++r) {
                int j = t * 16 + g * 4 + r;
                b2v[t * 4 + r] = nb2[j];
                w3v[t * 4 + r] = nw3[j];
            }
        const float b3c = nb3[0];

#pragma unroll
        for (int s = 0; s < 4; ++s) {
            int row = s * 16 + eL;
            FragU bf0, bf1;
            bf0.q = hbuf[row * 8 + ((    g) ^ (row & 7))];
            bf1.q = hbuf[row * 8 + ((4 + g) ^ (row & 7))];

            f32x4 ac[4];
#pragma unroll
            for (int t = 0; t < 4; ++t) {
                ac[t][0] = b2v[t * 4 + 0];
                ac[t][1] = b2v[t * 4 + 1];
                ac[t][2] = b2v[t * 4 + 2];
                ac[t][3] = b2v[t * 4 + 3];
                ac[t] = __builtin_amdgcn_mfma_f32_16x16x32_bf16(af[t][0].v, bf0.v, ac[t], 0, 0, 0);
                ac[t] = __builtin_amdgcn_mfma_f32_16x16x32_bf16(af[t][1].v, bf1.v, ac[t], 0, 0, 0);
            }

            float p = 0.f;
#pragma unroll
            for (int t = 0; t < 4; ++t)
#pragma unroll
                for (int r = 0; r < 4; ++r)
                    p = fmaf(fmaxf(ac[t][r], 0.f), w3v[t * 4 + r], p);

            p += __shfl_xor(p, 16);
            p += __shfl_xor(p, 32);

            if (lane < 16)
                unfbuf[s * 16 + lane] = p + b3c;
        }
    }

    const float unf = unfbuf[lane];

    // ================= MLP-M: unf -> sigmoid(out) =================
    {
        uint32_t pk[32];
#pragma unroll
        for (int k2 = 0; k2 < 32; ++k2) {
            int k0 = 2 * k2, k1 = 2 * k2 + 1;
            float h0 = fmaxf(fmaf(unf, mw1[k0], mb1[k0]), 0.f);
            float h1 = fmaxf(fmaf(unf, mw1[k1], mb1[k1]), 0.f);
            pk[k2] = cvt_pk_bf16(h0, h1);
        }
        uint4* rowp = &hbuf[lane * 8];
#pragma unroll
        for (int ch = 0; ch < 8; ++ch)
            rowp[ch ^ sw] = make_uint4(pk[4 * ch], pk[4 * ch + 1], pk[4 * ch + 2], pk[4 * ch + 3]);

        FragU af[4][2];
#pragma unroll
        for (int t = 0; t < 4; ++t)
#pragma unroll
            for (int h = 0; h < 2; ++h)
#pragma unroll
                for (int e2 = 0; e2 < 4; ++e2) {
                    int k0 = h * 32 + g * 8 + 2 * e2;
                    float v0 = mw2[(k0    ) * HID + t * 16 + eL];
                    float v1 = mw2[(k0 + 1) * HID + t * 16 + eL];
                    af[t][h].u[e2] = cvt_pk_bf16(v0, v1);
                }
        float b2v[16], w3v[16];
#pragma unroll
        for (int t = 0; t < 4; ++t)
#pragma unroll
            for (int r = 0; r < 4; ++r) {
                int j = t * 16 + g * 4 + r;
                b2v[t * 4 + r] = mb2[j];
                w3v[t * 4 + r] = mw3[j];
            }
        const float b3c = mb3[0];

#pragma unroll
        for (int s = 0; s < 4; ++s) {
            int row = s * 16 + eL;
            FragU bf0, bf1;
            bf0.q = hbuf[row * 8 + ((    g) ^ (row & 7))];
            bf1.q = hbuf[row * 8 + ((4 + g) ^ (row & 7))];

            f32x4 ac[4];
#pragma unroll
            for (int t = 0; t < 4; ++t) {
                ac[t][0] = b2v[t * 4 + 0];
                ac[t][1] = b2v[t * 4 + 1];
                ac[t][2] = b2v[t * 4 + 2];
                ac[t][3] = b2v[t * 4 + 3];
                ac[t] = __builtin_amdgcn_mfma_f32_16x16x32_bf16(af[t][0].v, bf0.v, ac[t], 0, 0, 0);
                ac[t] = __builtin_amdgcn_mfma_f32_16x16x32_bf16(af[t][1].v, bf1.v, ac[t], 0, 0, 0);
            }

            float p = 0.f;
#pragma unroll
            for (int t = 0; t < 4; ++t)
#pragma unroll
                for (int r = 0; r < 4; ++r)
                    p = fmaf(fmaxf(ac[t][r], 0.f), w3v[t * 4 + r], p);

            p += __shfl_xor(p, 16);
            p += __shfl_xor(p, 32);

            if (lane < 16) {
                float o = p + b3c;
                obuf[s * 16 + lane] = 1.0f / (1.0f + expf(-o));
            }
        }
    }

    // ---- segmented reduction over sorted gid, one atomic per run tail ----
    {
        const bool ok = idx < N;
        float v = ok ? obuf[lane] : 0.0f;
        int   gg = gid[i];

#pragma unroll
        for (int d = 1; d < 64; d <<= 1) {
            float vup = __shfl_up(v, d);
            int   gup = __shfl_up(gg, d);
            if (lane >= d && gup == gg) v += vup;
        }
        int gdn = __shfl_down(gg, 1);
        bool tail = (lane == 63) || (gdn != gg);
        if (tail)
            atomicAdd(&rd[gg], v);
    }
}

__global__ void readout_kernel(const float* __restrict__ rd,
                               float* __restrict__ out, int G)
{
    int g = blockIdx.x * blockDim.x + threadIdx.x;
    if (g < G) out[g] = 1.0f / (1.0f + expf(-rd[g]));
}

extern "C" void kernel_launch(void* const* d_in, const int* in_sizes, int n_in,
                              void* d_out, int out_size, void* d_ws, size_t ws_size,
                              hipStream_t stream)
{
    const float* nf  = (const float*)d_in[0];
    const float* ef  = (const float*)d_in[1];
    const int*   src = (const int*)  d_in[2];
    const int*   dst = (const int*)  d_in[3];
    const int*   gid = (const int*)  d_in[4];

    const float* e_w1 = (const float*)d_in[5];
    const float* e_b1 = (const float*)d_in[6];
    const float* e_w2 = (const float*)d_in[7];
    const float* e_b2 = (const float*)d_in[8];
    const float* e_w3 = (const float*)d_in[9];
    const float* e_b3 = (const float*)d_in[10];

    const float* n_w1 = (const float*)d_in[11];
    const float* n_b1 = (const float*)d_in[12];
    const float* n_w2 = (const float*)d_in[13];
    const float* n_b2 = (const float*)d_in[14];
    const float* n_w3 = (const float*)d_in[15];
    const float* n_b3 = (const float*)d_in[16];

    const float* m_w1 = (const float*)d_in[17];
    const float* m_b1 = (const float*)d_in[18];
    const float* m_w2 = (const float*)d_in[19];
    const float* m_b2 = (const float*)d_in[20];
    const float* m_w3 = (const float*)d_in[21];
    const float* m_b3 = (const float*)d_in[22];

    const int N = in_sizes[0];   // 50000 nodes
    const int E = in_sizes[2];   // 1600000 edges
    const int G = out_size;      // 512 graphs

    const int NW = (E + 63) / 64;                 // wave batches
    const int B  = (N + BKT_RANGE - 1) / BKT_RANGE;

    // ws layout (bucket path): recs[NW*64 uint2] | offs[NW u64] | partial[B*C*8192 f32] | agg[N] | rd[G]
    size_t recs_b   = (size_t)NW * 64 * sizeof(uint2);
    size_t offs_b   = (size_t)NW * sizeof(ull);
    size_t part_b   = (size_t)B * CCHUNK * BKT_RANGE * sizeof(float);
    size_t need     = recs_b + offs_b + part_b + ((size_t)N + G) * sizeof(float);
    bool   bucketok = (B <= 8) && (need <= ws_size);

    float* out = (float*)d_out;

    if (bucketok) {
        uint2* recs    = (uint2*)d_ws;
        ull*   offs    = (ull*)((char*)d_ws + recs_b);
        float* partial = (float*)((char*)d_ws + recs_b + offs_b);
        float* agg     = (float*)((char*)d_ws + recs_b + offs_b + part_b);
        float* rd      = agg + N;

        hipMemsetAsync(rd, 0, (size_t)G * sizeof(float), stream);

        edge_mlp_kernel<<<(E + 255) / 256, 256, 0, stream>>>(
            nf, ef, src, dst, e_w1, e_b1, e_w2, e_b2, e_w3, e_b3,
            recs, offs, nullptr, E, B, 0);

        bucket_accum_kernel<<<B * CCHUNK, 256, 0, stream>>>(
            recs, offs, partial, NW, B);

        bucket_reduce_kernel<<<(N + 255) / 256, 256, 0, stream>>>(
            partial, agg, N);

        node_mfma_kernel<<<(N + 63) / 64, 64, 0, stream>>>(
            nf, agg, gid,
            n_w1, n_b1, n_w2, n_b2, n_w3, n_b3,
            m_w1, m_b1, m_w2, m_b2, m_w3, m_b3,
            rd, N);

        readout_kernel<<<(G + 255) / 256, 256, 0, stream>>>(rd, out, G);
    } else {
        // fallback: fused atomic aggregation (round-4 path)
        float* agg = (float*)d_ws;
        float* rd  = agg + N;

        hipMemsetAsync(d_ws, 0, ((size_t)N + G) * sizeof(float), stream);

        edge_mlp_kernel<<<(E + 255) / 256, 256, 0, stream>>>(
            nf, ef, src, dst, e_w1, e_b1, e_w2, e_b2, e_w3, e_b3,
            nullptr, nullptr, agg, E, B, 1);

        node_mfma_kernel<<<(N + 63) / 64, 64, 0, stream>>>(
            nf, agg, gid,
            n_w1, n_b1, n_w2, n_b2, n_w3, n_b3,
            m_w1, m_b1, m_w2, m_b2, m_w3, m_b3,
            rd, N);

        readout_kernel<<<(G + 255) / 256, 256, 0, stream>>>(rd, out, G);
    }
}